// Round 3
// baseline (89.614 us; speedup 1.0000x reference)
//
#include <hip/hip_runtime.h>

#define N_PTS 65536
#define T_DIM 32
#define P_DIM 16

// Single fused kernel. Block = 64 points x 32 t. LDS: R-table 512 rows,
// stride 14 floats (conflict-free pstar gather: 14p mod 32 distinct for p<16),
// partials overlay the R region between barriers. 28.9 KB -> 5 blocks/CU.
__global__ __launch_bounds__(256) void fused_kernel(
    const float* __restrict__ pc,
    const float* __restrict__ w1,
    const float* __restrict__ b1,
    const float* __restrict__ w2,
    const float* __restrict__ b2,
    const float* __restrict__ d6,
    const float* __restrict__ pt,
    const float* __restrict__ gumbel,
    float* __restrict__ out_pc,
    float* __restrict__ out_idx,
    float* __restrict__ out_trans)
{
    __shared__ __align__(16) float smem[7168 + 64];  // R rows (overlaid by partials) + pstar
    const int tid  = threadIdx.x;
    const int lane = tid & 63;
    const int wv   = __builtin_amdgcn_readfirstlane(tid >> 6);
    const int n    = blockIdx.x * 64 + lane;

    const float x0 = pc[n*3+0], x1 = pc[n*3+1], x2 = pc[n*3+2];

    // ---- compute 2 R-table entries per thread (e = tid, tid+256); held in
    //      registers until after the reduce barrier (LDS region is overlaid) ----
    float Re[2][12];
    #pragma unroll
    for (int j=0;j<2;j++) {
        const int e = tid + j*256;
        const float* a = d6 + e*6;
        float a1x=a[0], a1y=a[1], a1z=a[2], a2x=a[3], a2y=a[4], a2z=a[5];
        float i1 = 1.0f / sqrtf(a1x*a1x + a1y*a1y + a1z*a1z);
        float b1x=a1x*i1, b1y=a1y*i1, b1z=a1z*i1;
        float d = b1x*a2x + b1y*a2y + b1z*a2z;
        float px = a2x - d*b1x, py = a2y - d*b1y, pz = a2z - d*b1z;
        float i2 = 1.0f / sqrtf(px*px + py*py + pz*pz);
        float c0=px*i2, c1=py*i2, c2=pz*i2;
        Re[j][0]=b1x; Re[j][1]=b1y; Re[j][2]=b1z;
        Re[j][3]=c0;  Re[j][4]=c1;  Re[j][5]=c2;
        Re[j][6]=b1y*c2 - b1z*c1;
        Re[j][7]=b1z*c0 - b1x*c2;
        Re[j][8]=b1x*c1 - b1y*c0;
        Re[j][9]=pt[e*3+0]; Re[j][10]=pt[e*3+1]; Re[j][11]=pt[e*3+2];
    }
    // block 0 writes trans_list while it's hot in registers
    if (blockIdx.x == 0) {
        #pragma unroll
        for (int j=0;j<2;j++) {
            float* o = out_trans + (tid + j*256)*16;
            o[0]=Re[j][0]; o[1]=Re[j][1]; o[2]=Re[j][2];  o[3]=Re[j][9];
            o[4]=Re[j][3]; o[5]=Re[j][4]; o[6]=Re[j][5];  o[7]=Re[j][10];
            o[8]=Re[j][6]; o[9]=Re[j][7]; o[10]=Re[j][8]; o[11]=Re[j][11];
            o[12]=0.f; o[13]=0.f; o[14]=0.f; o[15]=1.f;
        }
    }

    // gumbel prefetch (only wave 0 consumes it, after the reduce)
    float g[16];
    if (wv == 0) {
        const float4* g4 = (const float4*)(gumbel + (size_t)n*16);
        #pragma unroll
        for (int j=0;j<4;j++) { float4 v = g4[j]; g[4*j]=v.x; g[4*j+1]=v.y; g[4*j+2]=v.z; g[4*j+3]=v.w; }
    }

    // ---- Phase 1: partial MLP, wave wv covers k in [32wv, 32wv+32).
    //      All weight addresses wave-uniform -> scalar (s_load) path. ----
    float seg[16];
    if (wv == 0) {
        #pragma unroll
        for (int p=0;p<16;p++) seg[p] = b2[p];
    } else {
        #pragma unroll
        for (int p=0;p<16;p++) seg[p] = 0.f;
    }
    const int k0 = wv*32;
    #pragma unroll 2
    for (int kk=0;kk<32;kk++) {
        const int k = k0 + kk;
        float h = fmaf(w1[k*3+0], x0, b1[k]);
        h = fmaf(w1[k*3+1], x1, h);
        h = fmaf(w1[k*3+2], x2, h);
        h = fmaxf(h, 0.0f);
        #pragma unroll
        for (int p=0;p<16;p++) seg[p] = fmaf(w2[p*128+k], h, seg[p]);
    }
    // partials [wv][p][lane] in the (not-yet-written) R region
    #pragma unroll
    for (int p=0;p<16;p++) smem[wv*1024 + p*64 + lane] = seg[p];
    __syncthreads();

    // ---- Reduce + both argmaxes (wave 0; other blocks on the CU hide the idle) ----
    if (wv == 0) {
        float s[16];
        #pragma unroll
        for (int p=0;p<16;p++) {
            float v = smem[p*64 + lane] + smem[1024 + p*64 + lane];
            v += smem[2048 + p*64 + lane] + smem[3072 + p*64 + lane];
            s[p] = v;
        }
        float best = s[0]; int pseg = 0;
        #pragma unroll
        for (int p=1;p<16;p++) { if (s[p] > best) { best = s[p]; pseg = p; } }
        out_idx[n] = (float)pseg;
        float bg = s[0] + g[0]; int pstar = 0;
        #pragma unroll
        for (int p=1;p<16;p++) { float v = s[p] + g[p]; if (v > bg) { bg = v; pstar = p; } }
        smem[7168 + lane] = (float)pstar;
    }
    __syncthreads();

    // ---- Write R entries into LDS (stride 14; lane addr stride 14 -> 4-way, one-time) ----
    #pragma unroll
    for (int j=0;j<2;j++) {
        float* R = smem + (tid + j*256)*14;
        *(float2*)(R)    = make_float2(Re[j][0], Re[j][1]);
        *(float2*)(R+2)  = make_float2(Re[j][2], Re[j][3]);
        *(float2*)(R+4)  = make_float2(Re[j][4], Re[j][5]);
        *(float2*)(R+6)  = make_float2(Re[j][6], Re[j][7]);
        *(float2*)(R+8)  = make_float2(Re[j][8], Re[j][9]);
        *(float2*)(R+10) = make_float2(Re[j][10], Re[j][11]);
    }
    const int p = (int)smem[7168 + lane];   // written pre-B2, safe to read here
    __syncthreads();

    // ---- Phase 2: 8 transforms per thread (t = wv*8 + i), conflict-free gather ----
    const float* Rb = smem + p*14;
    #pragma unroll
    for (int i=0;i<8;i++) {
        const int t = wv*8 + i;
        const float* R = Rb + t*224;  // (t*16+p)*14
        float2 r01 = *(const float2*)(R);
        float2 r23 = *(const float2*)(R+2);
        float2 r45 = *(const float2*)(R+4);
        float2 r67 = *(const float2*)(R+6);
        float2 r8t = *(const float2*)(R+8);
        float2 t12 = *(const float2*)(R+10);
        float y0 = fmaf(r01.x, x0, r8t.y); y0 = fmaf(r01.y, x1, y0); y0 = fmaf(r23.x, x2, y0);
        float y1 = fmaf(r23.y, x0, t12.x); y1 = fmaf(r45.x, x1, y1); y1 = fmaf(r45.y, x2, y1);
        float y2 = fmaf(r67.x, x0, t12.y); y2 = fmaf(r67.y, x1, y2); y2 = fmaf(r8t.x, x2, y2);
        float* o = out_pc + ((size_t)t * N_PTS + n) * 3;
        o[0]=y0; o[1]=y1; o[2]=y2;
    }
}

extern "C" void kernel_launch(void* const* d_in, const int* in_sizes, int n_in,
                              void* d_out, int out_size, void* d_ws, size_t ws_size,
                              hipStream_t stream)
{
    const float* pc  = (const float*)d_in[0];
    const float* w1  = (const float*)d_in[1];
    const float* b1  = (const float*)d_in[2];
    const float* w2  = (const float*)d_in[3];
    const float* b2  = (const float*)d_in[4];
    const float* d6  = (const float*)d_in[5];
    const float* pt  = (const float*)d_in[6];
    const float* gum = (const float*)d_in[7];
    float* out = (float*)d_out;

    float* out_pc    = out;                        // T*N*3 = 6291456
    float* out_idx   = out + 6291456;              // N     = 65536
    float* out_trans = out + 6291456 + 65536;      // T*P*16 = 8192

    fused_kernel<<<1024, 256, 0, stream>>>(pc, w1, b1, w2, b2, d6, pt, gum,
                                           out_pc, out_idx, out_trans);
}

// Round 4
// 87.443 us; speedup vs baseline: 1.0248x; 1.0248x over previous
//
#include <hip/hip_runtime.h>

#define N_PTS 65536
#define T_DIM 32
#define P_DIM 16

// ws float layout:
//   [0, 7168)      R rows: (t*16+p)*14 = {R row-major (9), t (3), pad(2)}
//   [7168, 9728)   wpack: k*20 = {w1[k][0..2], b1[k], w2[0..15][k]}
//   [9728, 9744)   b2
__global__ void prep_kernel(const float* __restrict__ d6,
                            const float* __restrict__ pt,
                            const float* __restrict__ w1,
                            const float* __restrict__ b1,
                            const float* __restrict__ w2,
                            const float* __restrict__ b2,
                            float* __restrict__ ws,
                            float* __restrict__ out_trans)
{
    int idx = blockIdx.x * blockDim.x + threadIdx.x;
    if (idx < T_DIM * P_DIM) {
        const float* a = d6 + idx * 6;
        float a1x=a[0], a1y=a[1], a1z=a[2], a2x=a[3], a2y=a[4], a2z=a[5];
        float n1 = sqrtf(a1x*a1x + a1y*a1y + a1z*a1z);
        float b1x=a1x/n1, b1y=a1y/n1, b1z=a1z/n1;
        float d = b1x*a2x + b1y*a2y + b1z*a2z;
        float px = a2x - d*b1x, py = a2y - d*b1y, pz = a2z - d*b1z;
        float n2 = sqrtf(px*px + py*py + pz*pz);
        float b2x=px/n2, b2y=py/n2, b2z=pz/n2;
        float b3x = b1y*b2z - b1z*b2y;
        float b3y = b1z*b2x - b1x*b2z;
        float b3z = b1x*b2y - b1y*b2x;
        float t0 = pt[idx*3+0], t1 = pt[idx*3+1], t2 = pt[idx*3+2];
        float* R = ws + idx*14;
        R[0]=b1x; R[1]=b1y; R[2]=b1z;
        R[3]=b2x; R[4]=b2y; R[5]=b2z;
        R[6]=b3x; R[7]=b3y; R[8]=b3z;
        R[9]=t0;  R[10]=t1; R[11]=t2;
        R[12]=0.f; R[13]=0.f;
        float* o = out_trans + idx*16;
        o[0]=b1x; o[1]=b1y; o[2]=b1z;  o[3]=t0;
        o[4]=b2x; o[5]=b2y; o[6]=b2z;  o[7]=t1;
        o[8]=b3x; o[9]=b3y; o[10]=b3z; o[11]=t2;
        o[12]=0.f; o[13]=0.f; o[14]=0.f; o[15]=1.f;
    }
    int k = idx - 512;
    if (k >= 0 && k < 128) {
        float* wp = ws + 7168 + k*20;
        wp[0]=w1[k*3+0]; wp[1]=w1[k*3+1]; wp[2]=w1[k*3+2]; wp[3]=b1[k];
        #pragma unroll
        for (int p=0;p<16;p++) wp[4+p] = w2[p*128+k];
    }
    if (idx < 16) ws[9728+idx] = b2[idx];
}

// Block = 64 points, 4 waves. Phase 1: waves split k (32 each), packed weight
// rows via wave-uniform s_load; R-table prefetched into registers at start
// (overlaps the MLP), written to LDS after the reduce barrier. All waves
// redundantly reduce+argmax (pstar stays in VGPR). LDS 28 KB -> 5 blocks/CU.
__global__ __launch_bounds__(256) void fused_kernel(
    const float* __restrict__ pc,
    const float* __restrict__ gumbel,
    const float* __restrict__ ws,
    float* __restrict__ out_pc,
    float* __restrict__ out_idx)
{
    __shared__ __align__(16) float smem[7168];  // R rows; [0,4096) overlaid by partials
    const int tid  = threadIdx.x;
    const int lane = tid & 63;
    const int wv   = __builtin_amdgcn_readfirstlane(tid >> 6);
    const int n    = blockIdx.x * 64 + lane;

    const float x0 = pc[n*3+0], x1 = pc[n*3+1], x2 = pc[n*3+2];

    // ---- R-table register prefetch: 14 float2 per thread (issued now, used
    //      after B2 — overlaps with the s_load-bound MLP below) ----
    float2 rp[14];
    {
        const float2* src = (const float2*)ws;   // 3584 float2
        #pragma unroll
        for (int i=0;i<14;i++) rp[i] = src[tid + i*256];
    }

    // gumbel for this wave's 64 points (all 4 waves load same lines -> L1)
    float g[16];
    {
        const float4* g4 = (const float4*)(gumbel + (size_t)n*16);
        #pragma unroll
        for (int j=0;j<4;j++) { float4 v = g4[j]; g[4*j]=v.x; g[4*j+1]=v.y; g[4*j+2]=v.z; g[4*j+3]=v.w; }
    }

    // ---- Phase 1: partial MLP over k in [32wv, 32wv+32), packed rows ----
    const float* wpk = ws + 7168 + wv*32*20;
    float seg[16];
    if (wv == 0) {
        const float* b2p = ws + 9728;
        #pragma unroll
        for (int p=0;p<16;p++) seg[p] = b2p[p];
    } else {
        #pragma unroll
        for (int p=0;p<16;p++) seg[p] = 0.f;
    }
    #pragma unroll 8
    for (int k=0;k<32;k++) {
        const float* wp = wpk + k*20;
        float h = fmaf(wp[0], x0, wp[3]);
        h = fmaf(wp[1], x1, h);
        h = fmaf(wp[2], x2, h);
        h = fmaxf(h, 0.0f);
        #pragma unroll
        for (int p=0;p<16;p++) seg[p] = fmaf(wp[4+p], h, seg[p]);
    }
    // partials [wv][p][lane] — lane-major, 2 lanes/bank = free
    #pragma unroll
    for (int p=0;p<16;p++) smem[wv*1024 + p*64 + lane] = seg[p];
    __syncthreads();   // B1

    // ---- All waves: reduce + both argmaxes (redundant; no wave-0 serialize) ----
    int pstar;
    {
        float s[16];
        #pragma unroll
        for (int p=0;p<16;p++) {
            float v = smem[p*64 + lane] + smem[1024 + p*64 + lane];
            v += smem[2048 + p*64 + lane] + smem[3072 + p*64 + lane];
            s[p] = v;
        }
        float best = s[0]; int pseg = 0;
        #pragma unroll
        for (int p=1;p<16;p++) { if (s[p] > best) { best = s[p]; pseg = p; } }
        if (wv == 0) out_idx[n] = (float)pseg;
        float bg = s[0] + g[0]; pstar = 0;
        #pragma unroll
        for (int p=1;p<16;p++) { float v = s[p] + g[p]; if (v > bg) { bg = v; pstar = p; } }
    }
    __syncthreads();   // B2: partial reads done before overlay write

    // ---- Write prefetched R table into LDS ----
    {
        float2* dst = (float2*)smem;
        #pragma unroll
        for (int i=0;i<14;i++) dst[tid + i*256] = rp[i];
    }
    __syncthreads();   // B3

    // ---- Phase 2: 8 transforms per thread (t = wv*8 + i) ----
    // row stride 14: 14p mod 32 distinct for p<16 -> conflict-free gather
    const float* Rb = smem + pstar*14;
    #pragma unroll
    for (int i=0;i<8;i++) {
        const int t = wv*8 + i;
        const float* R = Rb + t*224;  // (t*16+p)*14
        float2 r01 = *(const float2*)(R);
        float2 r23 = *(const float2*)(R+2);
        float2 r45 = *(const float2*)(R+4);
        float2 r67 = *(const float2*)(R+6);
        float2 r8t = *(const float2*)(R+8);
        float2 t12 = *(const float2*)(R+10);
        float y0 = fmaf(r01.x, x0, r8t.y); y0 = fmaf(r01.y, x1, y0); y0 = fmaf(r23.x, x2, y0);
        float y1 = fmaf(r23.y, x0, t12.x); y1 = fmaf(r45.x, x1, y1); y1 = fmaf(r45.y, x2, y1);
        float y2 = fmaf(r67.x, x0, t12.y); y2 = fmaf(r67.y, x1, y2); y2 = fmaf(r8t.x, x2, y2);
        float* o = out_pc + ((size_t)t * N_PTS + n) * 3;
        o[0]=y0; o[1]=y1; o[2]=y2;
    }
}

extern "C" void kernel_launch(void* const* d_in, const int* in_sizes, int n_in,
                              void* d_out, int out_size, void* d_ws, size_t ws_size,
                              hipStream_t stream)
{
    const float* pc  = (const float*)d_in[0];
    const float* w1  = (const float*)d_in[1];
    const float* b1  = (const float*)d_in[2];
    const float* w2  = (const float*)d_in[3];
    const float* b2  = (const float*)d_in[4];
    const float* d6  = (const float*)d_in[5];
    const float* pt  = (const float*)d_in[6];
    const float* gum = (const float*)d_in[7];
    float* out = (float*)d_out;
    float* ws  = (float*)d_ws;

    float* out_pc    = out;                        // T*N*3 = 6291456
    float* out_idx   = out + 6291456;              // N     = 65536
    float* out_trans = out + 6291456 + 65536;      // T*P*16 = 8192

    prep_kernel<<<3, 256, 0, stream>>>(d6, pt, w1, b1, w2, b2, ws, out_trans);
    fused_kernel<<<1024, 256, 0, stream>>>(pc, gum, ws, out_pc, out_idx);
}